// Round 1
// baseline (7326.129 us; speedup 1.0000x reference)
//
#include <hip/hip_runtime.h>

#define N_NODES 100000
#define N_EDGES 3200000
#define F_IN 128
#define F_HID 128
#define F_OUT 32

// ---------------- degree / dinv ----------------
__global__ __launch_bounds__(256) void k_deg_init(float* deg) {
    int i = blockIdx.x * 256 + threadIdx.x;
    if (i < N_NODES) deg[i] = 1.0f;  // self-loop
}

__global__ __launch_bounds__(256) void k_deg_count(const int* __restrict__ ei, float* deg) {
    int e = blockIdx.x * 256 + threadIdx.x;
    if (e < N_EDGES) atomicAdd(&deg[ei[N_EDGES + e]], 1.0f);
}

__global__ __launch_bounds__(256) void k_dinv(float* deg) {
    int i = blockIdx.x * 256 + threadIdx.x;
    if (i < N_NODES) deg[i] = 1.0f / sqrtf(deg[i]);
}

// ---------------- GEMM1: g1 = (x @ W1) * dinv[row] ----------------
// W1 (128x128 f32 = 64KB) in LDS. One wave per row; lane owns outputs {lane, lane+64}.
__global__ __launch_bounds__(256) void k_gemm1(const float* __restrict__ x,
                                               const float* __restrict__ W1,
                                               const float* __restrict__ dinv,
                                               float* __restrict__ g1) {
    __shared__ float wlds[F_IN * F_HID];  // [k][j], 64 KB
    {
        const float4* w4 = (const float4*)W1;
        float4* wl4 = (float4*)wlds;
#pragma unroll
        for (int i = 0; i < 16; ++i)
            wl4[threadIdx.x + i * 256] = w4[threadIdx.x + i * 256];
    }
    __syncthreads();

    int lane = threadIdx.x & 63;
    int wid = blockIdx.x * 4 + (threadIdx.x >> 6);
    int nwaves = gridDim.x * 4;

    for (int n = wid; n < N_NODES; n += nwaves) {
        // wave cooperatively holds row n: lane l has x[n][2l], x[n][2l+1]
        float2 xr = *(const float2*)(x + n * F_IN + lane * 2);
        float a0 = 0.f, a1 = 0.f;
#pragma unroll
        for (int k = 0; k < F_IN; ++k) {
            float xk = __shfl((k & 1) ? xr.y : xr.x, k >> 1, 64);
            a0 = fmaf(xk, wlds[k * F_HID + lane], a0);
            a1 = fmaf(xk, wlds[k * F_HID + 64 + lane], a1);
        }
        float s = dinv[n];
        g1[n * F_HID + lane] = a0 * s;
        g1[n * F_HID + 64 + lane] = a1 * s;
    }
}

// ---------------- scatter1: acc1[dst] += g1[src]  (128 feats, float4/thread) -----
__global__ __launch_bounds__(256) void k_scatter1(const int* __restrict__ ei,
                                                  const float* __restrict__ g1,
                                                  float* __restrict__ acc1) {
    int idx = blockIdx.x * 256 + threadIdx.x;  // < 102,400,000
    int e = idx >> 5;
    int q = idx & 31;
    int s = ei[e];
    int d = ei[N_EDGES + e];
    float4 v = *(const float4*)(g1 + s * F_HID + q * 4);
    float* p = acc1 + d * F_HID + q * 4;
    atomicAdd(p + 0, v.x);
    atomicAdd(p + 1, v.y);
    atomicAdd(p + 2, v.z);
    atomicAdd(p + 3, v.w);
}

// ------- finalize layer1 + GEMM2 fused: g2 = relu(dinv*(acc1+g1)+b1) @ W2 * dinv ---
// block = 256 threads -> 8 nodes; W2 (16KB) + a_lds (4KB) in LDS.
__global__ __launch_bounds__(256) void k_fin1_gemm2(const float* __restrict__ acc1,
                                                    const float* __restrict__ g1,
                                                    const float* __restrict__ dinv,
                                                    const float* __restrict__ b1,
                                                    const float* __restrict__ W2,
                                                    float* __restrict__ g2) {
    __shared__ float w2l[F_HID * F_OUT];  // [k][j], 16 KB
    __shared__ float al[8][F_HID];        // 4 KB
    {
        const float4* w4 = (const float4*)W2;
        float4* wl4 = (float4*)w2l;
#pragma unroll
        for (int i = 0; i < 4; ++i)
            wl4[threadIdx.x + i * 256] = w4[threadIdx.x + i * 256];
    }
    int ns = threadIdx.x >> 5;  // node sub-index 0..7
    int j = threadIdx.x & 31;   // output class / feat-quad index
    int n = blockIdx.x * 8 + ns;

    {
        int f = j * 4;
        float4 va = *(const float4*)(acc1 + n * F_HID + f);
        float4 vg = *(const float4*)(g1 + n * F_HID + f);
        float4 vb = *(const float4*)(b1 + f);
        float di = dinv[n];
        al[ns][f + 0] = fmaxf(fmaf(di, va.x + vg.x, vb.x), 0.f);
        al[ns][f + 1] = fmaxf(fmaf(di, va.y + vg.y, vb.y), 0.f);
        al[ns][f + 2] = fmaxf(fmaf(di, va.z + vg.z, vb.z), 0.f);
        al[ns][f + 3] = fmaxf(fmaf(di, va.w + vg.w, vb.w), 0.f);
    }
    __syncthreads();

    float acc = 0.f;
#pragma unroll
    for (int k = 0; k < F_HID; ++k)
        acc = fmaf(al[ns][k], w2l[k * F_OUT + j], acc);
    g2[n * F_OUT + j] = acc * dinv[n];
}

// ---------------- scatter2: out[dst] += g2[src]  (32 feats, float4/thread) -------
__global__ __launch_bounds__(256) void k_scatter2(const int* __restrict__ ei,
                                                  const float* __restrict__ g2,
                                                  float* __restrict__ out) {
    int idx = blockIdx.x * 256 + threadIdx.x;  // < 25,600,000
    int e = idx >> 3;
    int q = idx & 7;
    int s = ei[e];
    int d = ei[N_EDGES + e];
    float4 v = *(const float4*)(g2 + s * F_OUT + q * 4);
    float* p = out + d * F_OUT + q * 4;
    atomicAdd(p + 0, v.x);
    atomicAdd(p + 1, v.y);
    atomicAdd(p + 2, v.z);
    atomicAdd(p + 3, v.w);
}

// ---------------- finalize layer 2 (in-place on d_out) ----------------
__global__ __launch_bounds__(256) void k_fin2(float* __restrict__ out,
                                              const float* __restrict__ g2,
                                              const float* __restrict__ dinv,
                                              const float* __restrict__ b2) {
    int idx = blockIdx.x * 256 + threadIdx.x;  // < 3,200,000
    int n = idx >> 5;
    int j = idx & 31;
    out[idx] = fmaf(dinv[n], out[idx] + g2[idx], b2[j]);
}

extern "C" void kernel_launch(void* const* d_in, const int* in_sizes, int n_in,
                              void* d_out, int out_size, void* d_ws, size_t ws_size,
                              hipStream_t stream) {
    const float* x  = (const float*)d_in[0];
    const int*   ei = (const int*)d_in[1];
    const float* W1 = (const float*)d_in[2];
    const float* b1 = (const float*)d_in[3];
    const float* W2 = (const float*)d_in[4];
    const float* b2 = (const float*)d_in[5];
    float* out = (float*)d_out;

    char* ws = (char*)d_ws;
    float* dinv = (float*)(ws);                              // 400 KB
    float* g1   = (float*)(ws + 524288);                     // 51.2 MB
    float* acc1 = (float*)(ws + 524288 + 51200000);          // 51.2 MB
    float* g2   = (float*)(ws + 524288 + 2 * 51200000);      // 12.8 MB

    k_deg_init<<<(N_NODES + 255) / 256, 256, 0, stream>>>(dinv);
    k_deg_count<<<N_EDGES / 256, 256, 0, stream>>>(ei, dinv);
    k_dinv<<<(N_NODES + 255) / 256, 256, 0, stream>>>(dinv);

    k_gemm1<<<2048, 256, 0, stream>>>(x, W1, dinv, g1);

    hipMemsetAsync(acc1, 0, (size_t)N_NODES * F_HID * 4, stream);
    k_scatter1<<<(N_EDGES / 256) * 32, 256, 0, stream>>>(ei, g1, acc1);

    k_fin1_gemm2<<<N_NODES / 8, 256, 0, stream>>>(acc1, g1, dinv, b1, W2, g2);

    hipMemsetAsync(out, 0, (size_t)N_NODES * F_OUT * 4, stream);
    k_scatter2<<<(N_EDGES / 256) * 8, 256, 0, stream>>>(ei, g2, out);
    k_fin2<<<(N_NODES * F_OUT) / 256, 256, 0, stream>>>(out, g2, dinv, b2);
}

// Round 2
// 1153.669 us; speedup vs baseline: 6.3503x; 6.3503x over previous
//
#include <hip/hip_runtime.h>

#define N_NODES 100000
#define N_EDGES 3200000
#define F_IN 128
#define F_HID 128
#define F_OUT 32
#define CAP 96  // padded CSR capacity; P(Poisson(32) > 96) ~ 4e-20 per node

// ---------------- degree histogram (int) ----------------
__global__ __launch_bounds__(256) void k_hist(const int* __restrict__ ei, int* __restrict__ deg_i) {
    int e = blockIdx.x * 256 + threadIdx.x;
    if (e < N_EDGES) atomicAdd(&deg_i[ei[N_EDGES + e]], 1);
}

__global__ __launch_bounds__(256) void k_dinv(const int* __restrict__ deg_i, float* __restrict__ dinv) {
    int i = blockIdx.x * 256 + threadIdx.x;
    if (i < N_NODES) dinv[i] = rsqrtf((float)(deg_i[i] + 1));  // +1 self-loop
}

// ---------------- bucket edges into padded CSR ----------------
__global__ __launch_bounds__(256) void k_bucket(const int* __restrict__ ei, int* __restrict__ cur,
                                                int* __restrict__ csr) {
    int e = blockIdx.x * 256 + threadIdx.x;
    if (e < N_EDGES) {
        int s = ei[e];
        int d = ei[N_EDGES + e];
        int pos = atomicAdd(&cur[d], 1);
        if (pos < CAP) csr[d * CAP + pos] = s;
    }
}

// ---------------- GEMM1: g1 = (x @ W1) * dinv[row] ----------------
__global__ __launch_bounds__(256) void k_gemm1(const float* __restrict__ x,
                                               const float* __restrict__ W1,
                                               const float* __restrict__ dinv,
                                               float* __restrict__ g1) {
    __shared__ float wlds[F_IN * F_HID];  // [k][j], 64 KB
    {
        const float4* w4 = (const float4*)W1;
        float4* wl4 = (float4*)wlds;
#pragma unroll
        for (int i = 0; i < 16; ++i)
            wl4[threadIdx.x + i * 256] = w4[threadIdx.x + i * 256];
    }
    __syncthreads();

    int lane = threadIdx.x & 63;
    int wid = blockIdx.x * 4 + (threadIdx.x >> 6);
    int nwaves = gridDim.x * 4;

    for (int n = wid; n < N_NODES; n += nwaves) {
        float2 xr = *(const float2*)(x + (size_t)n * F_IN + lane * 2);
        float a0 = 0.f, a1 = 0.f;
#pragma unroll
        for (int k = 0; k < F_IN; ++k) {
            float xk = __shfl((k & 1) ? xr.y : xr.x, k >> 1, 64);
            a0 = fmaf(xk, wlds[k * F_HID + lane], a0);
            a1 = fmaf(xk, wlds[k * F_HID + 64 + lane], a1);
        }
        float s = dinv[n];
        g1[(size_t)n * F_HID + lane] = a0 * s;
        g1[(size_t)n * F_HID + 64 + lane] = a1 * s;
    }
}

// ------- pull layer1 + relu/bias + GEMM2 fused, one wave per dst node -------
// a = relu(dinv[n]*(sum_in g1[src] + g1[n]) + b1);  g2[n] = (a @ W2) * dinv[n]
__global__ __launch_bounds__(256) void k_pull1_gemm2(const int* __restrict__ csr,
                                                     const int* __restrict__ deg_i,
                                                     const float* __restrict__ g1,
                                                     const float* __restrict__ dinv,
                                                     const float* __restrict__ b1,
                                                     const float* __restrict__ W2,
                                                     float* __restrict__ g2) {
    __shared__ float w2l[F_HID * F_OUT];  // [k][j], 16 KB
    __shared__ float al[4][F_HID];        // 2 KB
    {
        const float4* w4 = (const float4*)W2;
        float4* wl4 = (float4*)w2l;
#pragma unroll
        for (int i = 0; i < 4; ++i)
            wl4[threadIdx.x + i * 256] = w4[threadIdx.x + i * 256];
    }
    int lane = threadIdx.x & 63;
    int wv = threadIdx.x >> 6;
    int n = blockIdx.x * 4 + wv;  // grid is exactly N_NODES/4 blocks

    // gather: lane owns features {2*lane, 2*lane+1}
    float2 acc = *(const float2*)(g1 + (size_t)n * F_HID + lane * 2);  // self-loop term
    float accx2 = 0.f, accy2 = 0.f;
    int deg = deg_i[n];
    if (deg > CAP) deg = CAP;
    for (int e0 = 0; e0 < deg; e0 += 64) {
        int rem = deg - e0;
        int m = rem < 64 ? rem : 64;
        int sidx = (lane < m) ? csr[n * CAP + e0 + lane] : 0;
        int j = 0;
        for (; j + 1 < m; j += 2) {  // 2 loads in flight
            int s0 = __shfl(sidx, j);
            int s1 = __shfl(sidx, j + 1);
            float2 v0 = *(const float2*)(g1 + (size_t)s0 * F_HID + lane * 2);
            float2 v1 = *(const float2*)(g1 + (size_t)s1 * F_HID + lane * 2);
            acc.x += v0.x; acc.y += v0.y;
            accx2 += v1.x; accy2 += v1.y;
        }
        if (j < m) {
            int s0 = __shfl(sidx, j);
            float2 v0 = *(const float2*)(g1 + (size_t)s0 * F_HID + lane * 2);
            acc.x += v0.x; acc.y += v0.y;
        }
    }
    acc.x += accx2; acc.y += accy2;

    float di = dinv[n];
    float2 bb = *(const float2*)(b1 + lane * 2);
    float a0 = fmaxf(fmaf(di, acc.x, bb.x), 0.f);
    float a1 = fmaxf(fmaf(di, acc.y, bb.y), 0.f);
    *(float2*)(&al[wv][lane * 2]) = make_float2(a0, a1);
    __syncthreads();  // one barrier per thread, uniform (also covers W2 staging)

    // GEMM2: lane -> output j = lane&31, k-half = lane>>5
    int j = lane & 31, kh = lane >> 5;
    float sum = 0.f;
#pragma unroll
    for (int kk = 0; kk < 64; ++kk) {
        int k = kh * 64 + kk;
        sum = fmaf(al[wv][k], w2l[k * F_OUT + j], sum);
    }
    sum += __shfl_xor(sum, 32);
    if (lane < 32) g2[(size_t)n * F_OUT + j] = sum * di;
}

// ------- pull layer2 + bias, half-wave per dst node, writes d_out -------
__global__ __launch_bounds__(256) void k_pull2(const int* __restrict__ csr,
                                               const int* __restrict__ deg_i,
                                               const float* __restrict__ g2,
                                               const float* __restrict__ dinv,
                                               const float* __restrict__ b2,
                                               float* __restrict__ out) {
    int lane = threadIdx.x & 63;
    int wv = threadIdx.x >> 6;
    int half = lane >> 5, fl = lane & 31;
    int n = blockIdx.x * 8 + wv * 2 + half;  // grid is exactly N_NODES/8 blocks

    float acc = g2[(size_t)n * F_OUT + fl];  // self-loop term
    float acc2 = 0.f;
    int deg = deg_i[n];
    if (deg > CAP) deg = CAP;
    for (int e0 = 0; e0 < deg; e0 += 32) {
        int rem = deg - e0;
        int m = rem < 32 ? rem : 32;
        int sidx = (fl < m) ? csr[n * CAP + e0 + fl] : 0;
        int j = 0;
        for (; j + 1 < m; j += 2) {
            int s0 = __shfl(sidx, j, 32);
            int s1 = __shfl(sidx, j + 1, 32);
            acc += g2[(size_t)s0 * F_OUT + fl];
            acc2 += g2[(size_t)s1 * F_OUT + fl];
        }
        if (j < m) {
            int s0 = __shfl(sidx, j, 32);
            acc += g2[(size_t)s0 * F_OUT + fl];
        }
    }
    out[(size_t)n * F_OUT + fl] = fmaf(dinv[n], acc + acc2, b2[fl]);
}

extern "C" void kernel_launch(void* const* d_in, const int* in_sizes, int n_in,
                              void* d_out, int out_size, void* d_ws, size_t ws_size,
                              hipStream_t stream) {
    const float* x  = (const float*)d_in[0];
    const int*   ei = (const int*)d_in[1];
    const float* W1 = (const float*)d_in[2];
    const float* b1 = (const float*)d_in[3];
    const float* W2 = (const float*)d_in[4];
    const float* b2 = (const float*)d_in[5];
    float* out = (float*)d_out;

    char* ws = (char*)d_ws;
    int*   deg_i = (int*)(ws);                  // 400 KB
    int*   cur   = (int*)(ws + 524288);         // 400 KB
    float* dinv  = (float*)(ws + 1048576);      // 400 KB
    int*   csr   = (int*)(ws + 1572864);        // 100k*96*4 = 38.4 MB
    float* g1    = (float*)(ws + 41943040);     // 51.2 MB
    float* g2    = (float*)(ws + 94371840);     // 12.8 MB  (total ~107 MB)

    hipMemsetAsync(deg_i, 0, (size_t)N_NODES * 4, stream);
    hipMemsetAsync(cur, 0, (size_t)N_NODES * 4, stream);

    k_hist<<<N_EDGES / 256, 256, 0, stream>>>(ei, deg_i);
    k_dinv<<<(N_NODES + 255) / 256, 256, 0, stream>>>(deg_i, dinv);
    k_bucket<<<N_EDGES / 256, 256, 0, stream>>>(ei, cur, csr);

    k_gemm1<<<2048, 256, 0, stream>>>(x, W1, dinv, g1);

    k_pull1_gemm2<<<N_NODES / 4, 256, 0, stream>>>(csr, deg_i, g1, dinv, b1, W2, g2);
    k_pull2<<<N_NODES / 8, 256, 0, stream>>>(csr, deg_i, g2, dinv, b2, out);
}

// Round 3
// 609.389 us; speedup vs baseline: 12.0221x; 1.8932x over previous
//
#include <hip/hip_runtime.h>

#define N_NODES 100000
#define N_EDGES 3200000
#define F_IN 128
#define F_HID 128
#define F_OUT 32
#define CAP 96  // padded CSR capacity; P(Poisson(32) > 96) ~ 4e-20 per node

#define BM 64
#define BK 16
#define XPAD 68  // row stride for xT tile: 68*4B = 272B keeps 16B alignment, banks spread

// ---------------- bucket edges into padded CSR (cur ends up = in-degree) --------
__global__ __launch_bounds__(256) void k_bucket(const int* __restrict__ ei, int* __restrict__ cur,
                                                int* __restrict__ csr) {
    int e = blockIdx.x * 256 + threadIdx.x;
    if (e < N_EDGES) {
        int s = ei[e];
        int d = ei[N_EDGES + e];
        int pos = atomicAdd(&cur[d], 1);
        if (pos < CAP) csr[d * CAP + pos] = s;
    }
}

__global__ __launch_bounds__(256) void k_dinv(const int* __restrict__ deg_i, float* __restrict__ dinv) {
    int i = blockIdx.x * 256 + threadIdx.x;
    if (i < N_NODES) dinv[i] = rsqrtf((float)(deg_i[i] + 1));  // +1 self-loop
}

// ---------------- GEMM1: g1 = (x @ W1) * dinv[row] ----------------
// Register-tiled: BM=64 x BN=128 x BK=16, 256 threads, 4x8 acc/thread.
__global__ __launch_bounds__(256) void k_gemm1(const float* __restrict__ x,
                                               const float* __restrict__ W1,
                                               const float* __restrict__ dinv,
                                               float* __restrict__ g1) {
    __shared__ float xT[BK][XPAD];     // transposed x tile [k][m], 4.25 KB
    __shared__ float wt[BK][F_HID];    // W tile [k][j], 8 KB

    int tid = threadIdx.x;
    int m0 = blockIdx.x * BM;

    int rg = tid >> 4;     // row group 0..15
    int cg = tid & 15;     // col group 0..15
    int r0 = rg * 4;
    int c0 = cg * 8;

    // x-load addressing: thread t -> local row t>>2, k-quad (t&3)*4
    int lr = tid >> 2;
    int lk = (tid & 3) * 4;
    int gr = m0 + lr;
    int grc = gr < N_NODES ? gr : N_NODES - 1;
    const float* xrow = x + (size_t)grc * F_IN + lk;

    float acc[4][8];
#pragma unroll
    for (int i = 0; i < 4; ++i)
#pragma unroll
        for (int j = 0; j < 8; ++j) acc[i][j] = 0.f;

    for (int k0 = 0; k0 < F_IN; k0 += BK) {
        float4 v = *(const float4*)(xrow + k0);
        const float4* w4 = (const float4*)(W1 + (size_t)k0 * F_HID);
        float4 wv0 = w4[tid];
        float4 wv1 = w4[tid + 256];

        xT[lk + 0][lr] = v.x;
        xT[lk + 1][lr] = v.y;
        xT[lk + 2][lr] = v.z;
        xT[lk + 3][lr] = v.w;
        ((float4*)wt)[tid] = wv0;
        ((float4*)wt)[tid + 256] = wv1;
        __syncthreads();

#pragma unroll
        for (int k = 0; k < BK; ++k) {
            float a[4], b[8];
            *(float4*)a = *(const float4*)&xT[k][r0];
            *(float4*)(b + 0) = *(const float4*)&wt[k][c0];
            *(float4*)(b + 4) = *(const float4*)&wt[k][c0 + 4];
#pragma unroll
            for (int i = 0; i < 4; ++i)
#pragma unroll
                for (int j = 0; j < 8; ++j)
                    acc[i][j] = fmaf(a[i], b[j], acc[i][j]);
        }
        __syncthreads();
    }

#pragma unroll
    for (int i = 0; i < 4; ++i) {
        int n = m0 + r0 + i;
        if (n < N_NODES) {
            float s = dinv[n];
            float4 o0, o1;
            o0.x = acc[i][0] * s; o0.y = acc[i][1] * s; o0.z = acc[i][2] * s; o0.w = acc[i][3] * s;
            o1.x = acc[i][4] * s; o1.y = acc[i][5] * s; o1.z = acc[i][6] * s; o1.w = acc[i][7] * s;
            *(float4*)(g1 + (size_t)n * F_HID + c0) = o0;
            *(float4*)(g1 + (size_t)n * F_HID + c0 + 4) = o1;
        }
    }
}

// ------- pull layer1 + relu/bias + GEMM2 fused, one wave per dst node -------
__global__ __launch_bounds__(256) void k_pull1_gemm2(const int* __restrict__ csr,
                                                     const int* __restrict__ deg_i,
                                                     const float* __restrict__ g1,
                                                     const float* __restrict__ dinv,
                                                     const float* __restrict__ b1,
                                                     const float* __restrict__ W2,
                                                     float* __restrict__ g2) {
    __shared__ float w2l[F_HID * F_OUT];  // [k][j], 16 KB
    __shared__ float al[4][F_HID];        // 2 KB
    {
        const float4* w4 = (const float4*)W2;
        float4* wl4 = (float4*)w2l;
#pragma unroll
        for (int i = 0; i < 4; ++i)
            wl4[threadIdx.x + i * 256] = w4[threadIdx.x + i * 256];
    }
    int lane = threadIdx.x & 63;
    int wv = threadIdx.x >> 6;
    int n = blockIdx.x * 4 + wv;  // grid is exactly N_NODES/4 blocks

    float2 acc = *(const float2*)(g1 + (size_t)n * F_HID + lane * 2);  // self-loop
    float accx2 = 0.f, accy2 = 0.f;
    int deg = deg_i[n];
    if (deg > CAP) deg = CAP;
    for (int e0 = 0; e0 < deg; e0 += 64) {
        int rem = deg - e0;
        int m = rem < 64 ? rem : 64;
        int sidx = (lane < m) ? csr[n * CAP + e0 + lane] : 0;
        int j = 0;
        for (; j + 1 < m; j += 2) {
            int s0 = __shfl(sidx, j);
            int s1 = __shfl(sidx, j + 1);
            float2 v0 = *(const float2*)(g1 + (size_t)s0 * F_HID + lane * 2);
            float2 v1 = *(const float2*)(g1 + (size_t)s1 * F_HID + lane * 2);
            acc.x += v0.x; acc.y += v0.y;
            accx2 += v1.x; accy2 += v1.y;
        }
        if (j < m) {
            int s0 = __shfl(sidx, j);
            float2 v0 = *(const float2*)(g1 + (size_t)s0 * F_HID + lane * 2);
            acc.x += v0.x; acc.y += v0.y;
        }
    }
    acc.x += accx2; acc.y += accy2;

    float di = dinv[n];
    float2 bb = *(const float2*)(b1 + lane * 2);
    float a0 = fmaxf(fmaf(di, acc.x, bb.x), 0.f);
    float a1 = fmaxf(fmaf(di, acc.y, bb.y), 0.f);
    *(float2*)(&al[wv][lane * 2]) = make_float2(a0, a1);
    __syncthreads();

    int j = lane & 31, kh = lane >> 5;
    float sum = 0.f;
#pragma unroll
    for (int kk = 0; kk < 64; ++kk) {
        int k = kh * 64 + kk;
        sum = fmaf(al[wv][k], w2l[k * F_OUT + j], sum);
    }
    sum += __shfl_xor(sum, 32);
    if (lane < 32) g2[(size_t)n * F_OUT + j] = sum * di;
}

// ------- pull layer2 + bias, half-wave per dst node, writes d_out -------
__global__ __launch_bounds__(256) void k_pull2(const int* __restrict__ csr,
                                               const int* __restrict__ deg_i,
                                               const float* __restrict__ g2,
                                               const float* __restrict__ dinv,
                                               const float* __restrict__ b2,
                                               float* __restrict__ out) {
    int lane = threadIdx.x & 63;
    int wv = threadIdx.x >> 6;
    int half = lane >> 5, fl = lane & 31;
    int n = blockIdx.x * 8 + wv * 2 + half;  // grid is exactly N_NODES/8 blocks

    float acc = g2[(size_t)n * F_OUT + fl];  // self-loop
    float acc2 = 0.f;
    int deg = deg_i[n];
    if (deg > CAP) deg = CAP;
    for (int e0 = 0; e0 < deg; e0 += 32) {
        int rem = deg - e0;
        int m = rem < 32 ? rem : 32;
        int sidx = (fl < m) ? csr[n * CAP + e0 + fl] : 0;
        int j = 0;
        for (; j + 1 < m; j += 2) {
            int s0 = __shfl(sidx, j, 32);
            int s1 = __shfl(sidx, j + 1, 32);
            acc += g2[(size_t)s0 * F_OUT + fl];
            acc2 += g2[(size_t)s1 * F_OUT + fl];
        }
        if (j < m) {
            int s0 = __shfl(sidx, j, 32);
            acc += g2[(size_t)s0 * F_OUT + fl];
        }
    }
    out[(size_t)n * F_OUT + fl] = fmaf(dinv[n], acc + acc2, b2[fl]);
}

extern "C" void kernel_launch(void* const* d_in, const int* in_sizes, int n_in,
                              void* d_out, int out_size, void* d_ws, size_t ws_size,
                              hipStream_t stream) {
    const float* x  = (const float*)d_in[0];
    const int*   ei = (const int*)d_in[1];
    const float* W1 = (const float*)d_in[2];
    const float* b1 = (const float*)d_in[3];
    const float* W2 = (const float*)d_in[4];
    const float* b2 = (const float*)d_in[5];
    float* out = (float*)d_out;

    char* ws = (char*)d_ws;
    int*   cur   = (int*)(ws);                  // 400 KB (becomes in-degree)
    float* dinv  = (float*)(ws + 524288);       // 400 KB
    int*   csr   = (int*)(ws + 1048576);        // 100k*96*4 = 38.4 MB
    float* g1    = (float*)(ws + 41943040);     // 51.2 MB
    float* g2    = (float*)(ws + 94371840);     // 12.8 MB

    hipMemsetAsync(cur, 0, (size_t)N_NODES * 4, stream);
    k_bucket<<<N_EDGES / 256, 256, 0, stream>>>(ei, cur, csr);
    k_dinv<<<(N_NODES + 255) / 256, 256, 0, stream>>>(cur, dinv);

    k_gemm1<<<(N_NODES + BM - 1) / BM, 256, 0, stream>>>(x, W1, dinv, g1);

    k_pull1_gemm2<<<N_NODES / 4, 256, 0, stream>>>(csr, cur, g1, dinv, b1, W2, g2);
    k_pull2<<<N_NODES / 8, 256, 0, stream>>>(csr, cur, g2, dinv, b2, out);
}

// Round 4
// 411.794 us; speedup vs baseline: 17.7908x; 1.4798x over previous
//
#include <hip/hip_runtime.h>

#define N_NODES 100000
#define N_EDGES 3200000
#define F_IN 128
#define F_HID 128
#define F_OUT 32
#define CAP 96     // padded CSR capacity; P(Poisson(32) > 96) ~ 4e-20 per node

#define NBUCK 391  // coarse buckets of 256 dst nodes: (100000+255)>>8
#define CAPB 8960  // per-bucket staging capacity: mean 8192, sigma 90, +8.5 sigma
#define EPT 32     // edges per thread in k_part (block covers 8192 edges)

#define BM 64
#define BK 16
#define XPAD 68

// ---------- P1: partition edges into coarse dst-buckets (LDS-binned) ----------
__global__ __launch_bounds__(256) void k_part(const int* __restrict__ ei,
                                              int* __restrict__ gcur,
                                              unsigned long long* __restrict__ stage) {
    __shared__ int cnt[NBUCK];
    __shared__ int base[NBUCK];
    int tid = threadIdx.x;
    for (int i = tid; i < NBUCK; i += 256) cnt[i] = 0;
    __syncthreads();

    long e0 = (long)blockIdx.x * (256 * EPT);
#pragma unroll 4
    for (int i = 0; i < EPT; ++i) {
        long e = e0 + i * 256 + tid;
        if (e < N_EDGES) atomicAdd(&cnt[ei[N_EDGES + e] >> 8], 1);
    }
    __syncthreads();
    for (int i = tid; i < NBUCK; i += 256) {
        base[i] = atomicAdd(&gcur[i], cnt[i]);
        cnt[i] = 0;
    }
    __syncthreads();
#pragma unroll 4
    for (int i = 0; i < EPT; ++i) {
        long e = e0 + i * 256 + tid;
        if (e < N_EDGES) {
            int s = ei[e];
            int d = ei[N_EDGES + e];
            int b = d >> 8;
            int pos = base[b] + atomicAdd(&cnt[b], 1);
            if (pos < CAPB)
                stage[(size_t)b * CAPB + pos] = ((unsigned long long)(unsigned)d << 32) | (unsigned)s;
        }
    }
}

// ---------- P2: bucket -> padded CSR (writes stay in a 98KB L2 window) ----------
// Also emits degree and dinv (fused).
__global__ __launch_bounds__(256) void k_csr(const unsigned long long* __restrict__ stage,
                                             const int* __restrict__ gcur,
                                             int* __restrict__ csr,
                                             int* __restrict__ deg,
                                             float* __restrict__ dinv) {
    __shared__ int cnt[256];
    int b = blockIdx.x;
    int tid = threadIdx.x;
    cnt[tid] = 0;
    __syncthreads();

    int d0 = b << 8;
    int m = gcur[b];
    if (m > CAPB) m = CAPB;
    const unsigned long long* sp = stage + (size_t)b * CAPB;
    for (int i = tid; i < m; i += 256) {
        unsigned long long rec = sp[i];
        int s = (int)(unsigned)rec;
        int d = (int)(rec >> 32);
        int pos = atomicAdd(&cnt[d - d0], 1);
        if (pos < CAP) csr[(size_t)d * CAP + pos] = s;
    }
    __syncthreads();
    int dd = d0 + tid;
    if (dd < N_NODES) {
        int dg = cnt[tid];
        deg[dd] = dg;
        dinv[dd] = rsqrtf((float)(dg + 1));  // +1 self-loop
    }
}

// ---------------- GEMM1: g1 = (x @ W1) * dinv[row] ----------------
__global__ __launch_bounds__(256) void k_gemm1(const float* __restrict__ x,
                                               const float* __restrict__ W1,
                                               const float* __restrict__ dinv,
                                               float* __restrict__ g1) {
    __shared__ float xT[BK][XPAD];
    __shared__ float wt[BK][F_HID];

    int tid = threadIdx.x;
    int m0 = blockIdx.x * BM;

    int rg = tid >> 4;
    int cg = tid & 15;
    int r0 = rg * 4;
    int c0 = cg * 8;

    int lr = tid >> 2;
    int lk = (tid & 3) * 4;
    int gr = m0 + lr;
    int grc = gr < N_NODES ? gr : N_NODES - 1;
    const float* xrow = x + (size_t)grc * F_IN + lk;

    float acc[4][8];
#pragma unroll
    for (int i = 0; i < 4; ++i)
#pragma unroll
        for (int j = 0; j < 8; ++j) acc[i][j] = 0.f;

    for (int k0 = 0; k0 < F_IN; k0 += BK) {
        float4 v = *(const float4*)(xrow + k0);
        const float4* w4 = (const float4*)(W1 + (size_t)k0 * F_HID);
        float4 wv0 = w4[tid];
        float4 wv1 = w4[tid + 256];

        xT[lk + 0][lr] = v.x;
        xT[lk + 1][lr] = v.y;
        xT[lk + 2][lr] = v.z;
        xT[lk + 3][lr] = v.w;
        ((float4*)wt)[tid] = wv0;
        ((float4*)wt)[tid + 256] = wv1;
        __syncthreads();

#pragma unroll
        for (int k = 0; k < BK; ++k) {
            float a[4], b[8];
            *(float4*)a = *(const float4*)&xT[k][r0];
            *(float4*)(b + 0) = *(const float4*)&wt[k][c0];
            *(float4*)(b + 4) = *(const float4*)&wt[k][c0 + 4];
#pragma unroll
            for (int i = 0; i < 4; ++i)
#pragma unroll
                for (int j = 0; j < 8; ++j)
                    acc[i][j] = fmaf(a[i], b[j], acc[i][j]);
        }
        __syncthreads();
    }

#pragma unroll
    for (int i = 0; i < 4; ++i) {
        int n = m0 + r0 + i;
        if (n < N_NODES) {
            float s = dinv[n];
            float4 o0, o1;
            o0.x = acc[i][0] * s; o0.y = acc[i][1] * s; o0.z = acc[i][2] * s; o0.w = acc[i][3] * s;
            o1.x = acc[i][4] * s; o1.y = acc[i][5] * s; o1.z = acc[i][6] * s; o1.w = acc[i][7] * s;
            *(float4*)(g1 + (size_t)n * F_HID + c0) = o0;
            *(float4*)(g1 + (size_t)n * F_HID + c0 + 4) = o1;
        }
    }
}

// ------- pull layer1 + relu/bias + GEMM2 fused, one wave per dst node -------
__global__ __launch_bounds__(256) void k_pull1_gemm2(const int* __restrict__ csr,
                                                     const int* __restrict__ deg_i,
                                                     const float* __restrict__ g1,
                                                     const float* __restrict__ dinv,
                                                     const float* __restrict__ b1,
                                                     const float* __restrict__ W2,
                                                     float* __restrict__ g2) {
    __shared__ float w2l[F_HID * F_OUT];
    __shared__ float al[4][F_HID];
    {
        const float4* w4 = (const float4*)W2;
        float4* wl4 = (float4*)w2l;
#pragma unroll
        for (int i = 0; i < 4; ++i)
            wl4[threadIdx.x + i * 256] = w4[threadIdx.x + i * 256];
    }
    int lane = threadIdx.x & 63;
    int wv = threadIdx.x >> 6;
    int n = blockIdx.x * 4 + wv;

    float2 acc = *(const float2*)(g1 + (size_t)n * F_HID + lane * 2);  // self-loop
    float accx2 = 0.f, accy2 = 0.f;
    int deg = deg_i[n];
    if (deg > CAP) deg = CAP;
    for (int e0 = 0; e0 < deg; e0 += 64) {
        int rem = deg - e0;
        int m = rem < 64 ? rem : 64;
        int sidx = (lane < m) ? csr[n * CAP + e0 + lane] : 0;
        int j = 0;
        for (; j + 1 < m; j += 2) {
            int s0 = __shfl(sidx, j);
            int s1 = __shfl(sidx, j + 1);
            float2 v0 = *(const float2*)(g1 + (size_t)s0 * F_HID + lane * 2);
            float2 v1 = *(const float2*)(g1 + (size_t)s1 * F_HID + lane * 2);
            acc.x += v0.x; acc.y += v0.y;
            accx2 += v1.x; accy2 += v1.y;
        }
        if (j < m) {
            int s0 = __shfl(sidx, j);
            float2 v0 = *(const float2*)(g1 + (size_t)s0 * F_HID + lane * 2);
            acc.x += v0.x; acc.y += v0.y;
        }
    }
    acc.x += accx2; acc.y += accy2;

    float di = dinv[n];
    float2 bb = *(const float2*)(b1 + lane * 2);
    float a0 = fmaxf(fmaf(di, acc.x, bb.x), 0.f);
    float a1 = fmaxf(fmaf(di, acc.y, bb.y), 0.f);
    *(float2*)(&al[wv][lane * 2]) = make_float2(a0, a1);
    __syncthreads();

    int j = lane & 31, kh = lane >> 5;
    float sum = 0.f;
#pragma unroll
    for (int kk = 0; kk < 64; ++kk) {
        int k = kh * 64 + kk;
        sum = fmaf(al[wv][k], w2l[k * F_OUT + j], sum);
    }
    sum += __shfl_xor(sum, 32);
    if (lane < 32) g2[(size_t)n * F_OUT + j] = sum * di;
}

// ------- pull layer2 + bias, half-wave per dst node, writes d_out -------
__global__ __launch_bounds__(256) void k_pull2(const int* __restrict__ csr,
                                               const int* __restrict__ deg_i,
                                               const float* __restrict__ g2,
                                               const float* __restrict__ dinv,
                                               const float* __restrict__ b2,
                                               float* __restrict__ out) {
    int lane = threadIdx.x & 63;
    int wv = threadIdx.x >> 6;
    int half = lane >> 5, fl = lane & 31;
    int n = blockIdx.x * 8 + wv * 2 + half;

    float acc = g2[(size_t)n * F_OUT + fl];  // self-loop
    float acc2 = 0.f;
    int deg = deg_i[n];
    if (deg > CAP) deg = CAP;
    for (int e0 = 0; e0 < deg; e0 += 32) {
        int rem = deg - e0;
        int m = rem < 32 ? rem : 32;
        int sidx = (fl < m) ? csr[n * CAP + e0 + fl] : 0;
        int j = 0;
        for (; j + 1 < m; j += 2) {
            int s0 = __shfl(sidx, j, 32);
            int s1 = __shfl(sidx, j + 1, 32);
            acc += g2[(size_t)s0 * F_OUT + fl];
            acc2 += g2[(size_t)s1 * F_OUT + fl];
        }
        if (j < m) {
            int s0 = __shfl(sidx, j, 32);
            acc += g2[(size_t)s0 * F_OUT + fl];
        }
    }
    out[(size_t)n * F_OUT + fl] = fmaf(dinv[n], acc + acc2, b2[fl]);
}

extern "C" void kernel_launch(void* const* d_in, const int* in_sizes, int n_in,
                              void* d_out, int out_size, void* d_ws, size_t ws_size,
                              hipStream_t stream) {
    const float* x  = (const float*)d_in[0];
    const int*   ei = (const int*)d_in[1];
    const float* W1 = (const float*)d_in[2];
    const float* b1 = (const float*)d_in[3];
    const float* W2 = (const float*)d_in[4];
    const float* b2 = (const float*)d_in[5];
    float* out = (float*)d_out;

    char* ws = (char*)d_ws;
    int*   deg   = (int*)(ws);                   // 400 KB (pad to 512 KB)
    float* dinv  = (float*)(ws + 524288);        // 400 KB (pad to 512 KB)
    int*   gcur  = (int*)(ws + 1048576);         // 4 KB
    int*   csr   = (int*)(ws + 1052672);         // 38.4 MB
    float* g1    = (float*)(ws + 39452672);      // 51.2 MB
    float* g2    = (float*)(ws + 90652672);      // 12.8 MB (end ~103.5 MB)
    // staging overlays g1: fully consumed by k_csr before k_gemm1 writes g1
    unsigned long long* stage = (unsigned long long*)(ws + 39452672);  // 28.0 MB

    hipMemsetAsync(gcur, 0, 4096, stream);
    k_part<<<(N_EDGES + 256 * EPT - 1) / (256 * EPT), 256, 0, stream>>>(ei, gcur, stage);
    k_csr<<<NBUCK, 256, 0, stream>>>(stage, gcur, csr, deg, dinv);

    k_gemm1<<<(N_NODES + BM - 1) / BM, 256, 0, stream>>>(x, W1, dinv, g1);

    k_pull1_gemm2<<<N_NODES / 4, 256, 0, stream>>>(csr, deg, g1, dinv, b1, W2, g2);
    k_pull2<<<N_NODES / 8, 256, 0, stream>>>(csr, deg, g2, dinv, b2, out);
}

// Round 5
// 322.277 us; speedup vs baseline: 22.7324x; 1.2778x over previous
//
#include <hip/hip_runtime.h>

#define N_NODES 100000
#define N_EDGES 3200000
#define F_IN 128
#define F_HID 128
#define F_OUT 32
#define CAP 96     // padded CSR capacity; P(Poisson(32) > 96) ~ 4e-20 per node

#define NBUCK 391  // coarse buckets of 256 dst nodes
#define CAPB 8960  // per-bucket staging capacity
#define EPT 32     // edges per thread in k_part

#define BM 64
#define BK 16
#define XPAD 68

// pack two floats to bf16x2 (RNE)
__device__ inline unsigned pack_bf16(float a, float b) {
    unsigned ua = __float_as_uint(a);
    ua = (ua + 0x7fffu + ((ua >> 16) & 1u)) >> 16;
    unsigned ub = __float_as_uint(b);
    ub = (ub + 0x7fffu + ((ub >> 16) & 1u)) >> 16;
    return ua | (ub << 16);
}

// ---------- P1: partition edges into coarse dst-buckets (LDS-binned) ----------
__global__ __launch_bounds__(256) void k_part(const int* __restrict__ ei,
                                              int* __restrict__ gcur,
                                              unsigned long long* __restrict__ stage) {
    __shared__ int cnt[NBUCK];
    __shared__ int base[NBUCK];
    int tid = threadIdx.x;
    for (int i = tid; i < NBUCK; i += 256) cnt[i] = 0;
    __syncthreads();

    long e0 = (long)blockIdx.x * (256 * EPT);
#pragma unroll 4
    for (int i = 0; i < EPT; ++i) {
        long e = e0 + i * 256 + tid;
        if (e < N_EDGES) atomicAdd(&cnt[ei[N_EDGES + e] >> 8], 1);
    }
    __syncthreads();
    for (int i = tid; i < NBUCK; i += 256) {
        base[i] = atomicAdd(&gcur[i], cnt[i]);
        cnt[i] = 0;
    }
    __syncthreads();
#pragma unroll 4
    for (int i = 0; i < EPT; ++i) {
        long e = e0 + i * 256 + tid;
        if (e < N_EDGES) {
            int s = ei[e];
            int d = ei[N_EDGES + e];
            int b = d >> 8;
            int pos = base[b] + atomicAdd(&cnt[b], 1);
            if (pos < CAPB)
                stage[(size_t)b * CAPB + pos] = ((unsigned long long)(unsigned)d << 32) | (unsigned)s;
        }
    }
}

// ---------- P2: bucket -> padded CSR; emits degree and dinv ----------
__global__ __launch_bounds__(256) void k_csr(const unsigned long long* __restrict__ stage,
                                             const int* __restrict__ gcur,
                                             int* __restrict__ csr,
                                             int* __restrict__ deg,
                                             float* __restrict__ dinv) {
    __shared__ int cnt[256];
    int b = blockIdx.x;
    int tid = threadIdx.x;
    cnt[tid] = 0;
    __syncthreads();

    int d0 = b << 8;
    int m = gcur[b];
    if (m > CAPB) m = CAPB;
    const unsigned long long* sp = stage + (size_t)b * CAPB;
    for (int i = tid; i < m; i += 256) {
        unsigned long long rec = sp[i];
        int s = (int)(unsigned)rec;
        int d = (int)(rec >> 32);
        int pos = atomicAdd(&cnt[d - d0], 1);
        if (pos < CAP) csr[(size_t)d * CAP + pos] = s;
    }
    __syncthreads();
    int dd = d0 + tid;
    if (dd < N_NODES) {
        int dg = cnt[tid];
        deg[dd] = dg;
        dinv[dd] = rsqrtf((float)(dg + 1));  // +1 self-loop
    }
}

// ---------------- GEMM1: g1 = bf16( (x @ W1) * dinv[row] ) ----------------
__global__ __launch_bounds__(256) void k_gemm1(const float* __restrict__ x,
                                               const float* __restrict__ W1,
                                               const float* __restrict__ dinv,
                                               unsigned* __restrict__ g1u) {
    __shared__ float xT[BK][XPAD];
    __shared__ float wt[BK][F_HID];

    int tid = threadIdx.x;
    int m0 = blockIdx.x * BM;

    int rg = tid >> 4;
    int cg = tid & 15;
    int r0 = rg * 4;
    int c0 = cg * 8;

    int lr = tid >> 2;
    int lk = (tid & 3) * 4;
    int gr = m0 + lr;
    int grc = gr < N_NODES ? gr : N_NODES - 1;
    const float* xrow = x + (size_t)grc * F_IN + lk;

    float acc[4][8];
#pragma unroll
    for (int i = 0; i < 4; ++i)
#pragma unroll
        for (int j = 0; j < 8; ++j) acc[i][j] = 0.f;

    for (int k0 = 0; k0 < F_IN; k0 += BK) {
        float4 v = *(const float4*)(xrow + k0);
        const float4* w4 = (const float4*)(W1 + (size_t)k0 * F_HID);
        float4 wv0 = w4[tid];
        float4 wv1 = w4[tid + 256];

        xT[lk + 0][lr] = v.x;
        xT[lk + 1][lr] = v.y;
        xT[lk + 2][lr] = v.z;
        xT[lk + 3][lr] = v.w;
        ((float4*)wt)[tid] = wv0;
        ((float4*)wt)[tid + 256] = wv1;
        __syncthreads();

#pragma unroll
        for (int k = 0; k < BK; ++k) {
            float a[4], b[8];
            *(float4*)a = *(const float4*)&xT[k][r0];
            *(float4*)(b + 0) = *(const float4*)&wt[k][c0];
            *(float4*)(b + 4) = *(const float4*)&wt[k][c0 + 4];
#pragma unroll
            for (int i = 0; i < 4; ++i)
#pragma unroll
                for (int j = 0; j < 8; ++j)
                    acc[i][j] = fmaf(a[i], b[j], acc[i][j]);
        }
        __syncthreads();
    }

#pragma unroll
    for (int i = 0; i < 4; ++i) {
        int n = m0 + r0 + i;
        if (n < N_NODES) {
            float s = dinv[n];
            uint4 o;
            o.x = pack_bf16(acc[i][0] * s, acc[i][1] * s);
            o.y = pack_bf16(acc[i][2] * s, acc[i][3] * s);
            o.z = pack_bf16(acc[i][4] * s, acc[i][5] * s);
            o.w = pack_bf16(acc[i][6] * s, acc[i][7] * s);
            *(uint4*)(g1u + (size_t)n * 64 + (c0 >> 1)) = o;
        }
    }
}

// ------- pull layer1 + relu/bias + GEMM2 fused, one wave per dst node -------
// gathers bf16x2 per lane (4B), accumulates f32
__global__ __launch_bounds__(256) void k_pull1_gemm2(const int* __restrict__ csr,
                                                     const int* __restrict__ deg_i,
                                                     const unsigned* __restrict__ g1u,
                                                     const float* __restrict__ dinv,
                                                     const float* __restrict__ b1,
                                                     const float* __restrict__ W2,
                                                     unsigned* __restrict__ g2u) {
    __shared__ float w2l[F_HID * F_OUT];
    __shared__ float al[4][F_HID];
    {
        const float4* w4 = (const float4*)W2;
        float4* wl4 = (float4*)w2l;
#pragma unroll
        for (int i = 0; i < 4; ++i)
            wl4[threadIdx.x + i * 256] = w4[threadIdx.x + i * 256];
    }
    int lane = threadIdx.x & 63;
    int wv = threadIdx.x >> 6;
    int n = blockIdx.x * 4 + wv;

    unsigned u0 = g1u[(size_t)n * 64 + lane];  // self-loop
    float ax = __uint_as_float(u0 << 16), ay = __uint_as_float(u0 & 0xffff0000u);
    float ax2 = 0.f, ay2 = 0.f;
    int deg = deg_i[n];
    if (deg > CAP) deg = CAP;
    for (int e0 = 0; e0 < deg; e0 += 64) {
        int rem = deg - e0;
        int m = rem < 64 ? rem : 64;
        int sidx = (lane < m) ? csr[n * CAP + e0 + lane] : 0;
        int j = 0;
        for (; j + 1 < m; j += 2) {
            int s0 = __shfl(sidx, j);
            int s1 = __shfl(sidx, j + 1);
            unsigned v0 = g1u[(size_t)s0 * 64 + lane];
            unsigned v1 = g1u[(size_t)s1 * 64 + lane];
            ax += __uint_as_float(v0 << 16);
            ay += __uint_as_float(v0 & 0xffff0000u);
            ax2 += __uint_as_float(v1 << 16);
            ay2 += __uint_as_float(v1 & 0xffff0000u);
        }
        if (j < m) {
            int s0 = __shfl(sidx, j);
            unsigned v0 = g1u[(size_t)s0 * 64 + lane];
            ax += __uint_as_float(v0 << 16);
            ay += __uint_as_float(v0 & 0xffff0000u);
        }
    }
    ax += ax2; ay += ay2;

    float di = dinv[n];
    float2 bb = *(const float2*)(b1 + lane * 2);
    float a0 = fmaxf(fmaf(di, ax, bb.x), 0.f);
    float a1 = fmaxf(fmaf(di, ay, bb.y), 0.f);
    *(float2*)(&al[wv][lane * 2]) = make_float2(a0, a1);
    __syncthreads();

    int j = lane & 31, kh = lane >> 5;
    float sum = 0.f;
#pragma unroll
    for (int kk = 0; kk < 64; ++kk) {
        int k = kh * 64 + kk;
        sum = fmaf(al[wv][k], w2l[k * F_OUT + j], sum);
    }
    sum += __shfl_xor(sum, 32);
    float sv = sum * di;  // valid on lanes 0..31
    int fl16 = lane & 15;
    float sa = __shfl(sv, fl16 * 2);
    float sb = __shfl(sv, fl16 * 2 + 1);
    if (lane < 16) g2u[(size_t)n * 16 + fl16] = pack_bf16(sa, sb);
}

// ------- pull layer2 + bias, quarter-wave (16 lanes) per dst node -------
__global__ __launch_bounds__(256) void k_pull2(const int* __restrict__ csr,
                                               const int* __restrict__ deg_i,
                                               const unsigned* __restrict__ g2u,
                                               const float* __restrict__ dinv,
                                               const float* __restrict__ b2,
                                               float* __restrict__ out) {
    int lane = threadIdx.x & 63;
    int wv = threadIdx.x >> 6;
    int qw = lane >> 4, fl = lane & 15;
    int n = blockIdx.x * 16 + wv * 4 + qw;

    unsigned u0 = g2u[(size_t)n * 16 + fl];  // self-loop
    float ax = __uint_as_float(u0 << 16), ay = __uint_as_float(u0 & 0xffff0000u);
    float ax2 = 0.f, ay2 = 0.f;
    int deg = deg_i[n];
    if (deg > CAP) deg = CAP;
    for (int e0 = 0; e0 < deg; e0 += 16) {
        int rem = deg - e0;
        int m = rem < 16 ? rem : 16;
        int sidx = (fl < m) ? csr[n * CAP + e0 + fl] : 0;
        int j = 0;
        for (; j + 1 < m; j += 2) {
            int s0 = __shfl(sidx, j, 16);
            int s1 = __shfl(sidx, j + 1, 16);
            unsigned v0 = g2u[(size_t)s0 * 16 + fl];
            unsigned v1 = g2u[(size_t)s1 * 16 + fl];
            ax += __uint_as_float(v0 << 16);
            ay += __uint_as_float(v0 & 0xffff0000u);
            ax2 += __uint_as_float(v1 << 16);
            ay2 += __uint_as_float(v1 & 0xffff0000u);
        }
        if (j < m) {
            int s0 = __shfl(sidx, j, 16);
            unsigned v0 = g2u[(size_t)s0 * 16 + fl];
            ax += __uint_as_float(v0 << 16);
            ay += __uint_as_float(v0 & 0xffff0000u);
        }
    }
    ax += ax2; ay += ay2;

    float di = dinv[n];
    float2 bb = *(const float2*)(b2 + fl * 2);
    float2 o;
    o.x = fmaf(di, ax, bb.x);
    o.y = fmaf(di, ay, bb.y);
    *(float2*)(out + (size_t)n * F_OUT + fl * 2) = o;
}

extern "C" void kernel_launch(void* const* d_in, const int* in_sizes, int n_in,
                              void* d_out, int out_size, void* d_ws, size_t ws_size,
                              hipStream_t stream) {
    const float* x  = (const float*)d_in[0];
    const int*   ei = (const int*)d_in[1];
    const float* W1 = (const float*)d_in[2];
    const float* b1 = (const float*)d_in[3];
    const float* W2 = (const float*)d_in[4];
    const float* b2 = (const float*)d_in[5];
    float* out = (float*)d_out;

    char* ws = (char*)d_ws;
    int*      deg   = (int*)(ws);                        // 400 KB (pad 512 KB)
    float*    dinv  = (float*)(ws + 524288);             // 400 KB (pad 512 KB)
    int*      gcur  = (int*)(ws + 1048576);              // 4 KB (pad 512 KB)
    int*      csr   = (int*)(ws + 1572864);              // 38.4 MB
    unsigned long long* stage = (unsigned long long*)(ws + 40000000);  // 28.0 MB
    unsigned* g1u   = (unsigned*)(ws + 68028416);        // 25.6 MB
    unsigned* g2u   = (unsigned*)(ws + 93628416);        // 6.4 MB (end ~100 MB)

    hipMemsetAsync(gcur, 0, 4096, stream);
    k_part<<<(N_EDGES + 256 * EPT - 1) / (256 * EPT), 256, 0, stream>>>(ei, gcur, stage);
    k_csr<<<NBUCK, 256, 0, stream>>>(stage, gcur, csr, deg, dinv);

    k_gemm1<<<(N_NODES + BM - 1) / BM, 256, 0, stream>>>(x, W1, dinv, g1u);

    k_pull1_gemm2<<<N_NODES / 4, 256, 0, stream>>>(csr, deg, g1u, dinv, b1, W2, g2u);
    k_pull2<<<N_NODES / 16, 256, 0, stream>>>(csr, deg, g2u, dinv, b2, out);
}

// Round 7
// 301.349 us; speedup vs baseline: 24.3111x; 1.0694x over previous
//
#include <hip/hip_runtime.h>

#define N_NODES 100000
#define N_EDGES 3200000
#define F_IN 128
#define F_HID 128
#define F_OUT 32
#define CAP 96     // padded CSR capacity; P(Poisson(32) > 96) ~ 4e-20 per node

#define NBUCK 391  // coarse buckets of 256 dst nodes
#define CAPB 8960  // per-bucket staging capacity
#define EPT 32     // edges per thread in k_part

#define BM 64
#define BK 16
#define XPAD 68

typedef float f32x2 __attribute__((ext_vector_type(2)));

// pack two floats to bf16x2 (RNE)
__device__ inline unsigned pack_bf16(float a, float b) {
    unsigned ua = __float_as_uint(a);
    ua = (ua + 0x7fffu + ((ua >> 16) & 1u)) >> 16;
    unsigned ub = __float_as_uint(b);
    ub = (ub + 0x7fffu + ((ub >> 16) & 1u)) >> 16;
    return ua | (ub << 16);
}
__device__ inline float lo16(unsigned u) { return __uint_as_float(u << 16); }
__device__ inline float hi16(unsigned u) { return __uint_as_float(u & 0xffff0000u); }

// ---------- P1: partition edges into coarse dst-buckets (LDS-binned) ----------
__global__ __launch_bounds__(256) void k_part(const int* __restrict__ ei,
                                              int* __restrict__ gcur,
                                              unsigned long long* __restrict__ stage) {
    __shared__ int cnt[NBUCK];
    __shared__ int base[NBUCK];
    int tid = threadIdx.x;
    for (int i = tid; i < NBUCK; i += 256) cnt[i] = 0;
    __syncthreads();

    long e0 = (long)blockIdx.x * (256 * EPT);
#pragma unroll 4
    for (int i = 0; i < EPT; ++i) {
        long e = e0 + i * 256 + tid;
        if (e < N_EDGES) atomicAdd(&cnt[ei[N_EDGES + e] >> 8], 1);
    }
    __syncthreads();
    for (int i = tid; i < NBUCK; i += 256) {
        base[i] = atomicAdd(&gcur[i], cnt[i]);
        cnt[i] = 0;
    }
    __syncthreads();
#pragma unroll 4
    for (int i = 0; i < EPT; ++i) {
        long e = e0 + i * 256 + tid;
        if (e < N_EDGES) {
            int s = ei[e];
            int d = ei[N_EDGES + e];
            int b = d >> 8;
            int pos = base[b] + atomicAdd(&cnt[b], 1);
            if (pos < CAPB)
                stage[(size_t)b * CAPB + pos] = ((unsigned long long)(unsigned)d << 32) | (unsigned)s;
        }
    }
}

// ---------- P2: bucket -> padded CSR; emits degree and dinv ----------
__global__ __launch_bounds__(256) void k_csr(const unsigned long long* __restrict__ stage,
                                             const int* __restrict__ gcur,
                                             int* __restrict__ csr,
                                             int* __restrict__ deg,
                                             float* __restrict__ dinv) {
    __shared__ int cnt[256];
    int b = blockIdx.x;
    int tid = threadIdx.x;
    cnt[tid] = 0;
    __syncthreads();

    int d0 = b << 8;
    int m = gcur[b];
    if (m > CAPB) m = CAPB;
    const unsigned long long* sp = stage + (size_t)b * CAPB;
    for (int i = tid; i < m; i += 256) {
        unsigned long long rec = __builtin_nontemporal_load(sp + i);
        int s = (int)(unsigned)rec;
        int d = (int)(rec >> 32);
        int pos = atomicAdd(&cnt[d - d0], 1);
        if (pos < CAP) csr[(size_t)d * CAP + pos] = s;
    }
    __syncthreads();
    int dd = d0 + tid;
    if (dd < N_NODES) {
        int dg = cnt[tid];
        deg[dd] = dg;
        dinv[dd] = rsqrtf((float)(dg + 1));  // +1 self-loop
    }
}

// ---------------- GEMM1: g1 = bf16( (x @ W1) * dinv[row] ) ----------------
__global__ __launch_bounds__(256) void k_gemm1(const float* __restrict__ x,
                                               const float* __restrict__ W1,
                                               const float* __restrict__ dinv,
                                               unsigned* __restrict__ g1u) {
    __shared__ float xT[BK][XPAD];
    __shared__ float wt[BK][F_HID];

    int tid = threadIdx.x;
    int m0 = blockIdx.x * BM;

    int rg = tid >> 4;
    int cg = tid & 15;
    int r0 = rg * 4;
    int c0 = cg * 8;

    int lr = tid >> 2;
    int lk = (tid & 3) * 4;
    int gr = m0 + lr;
    int grc = gr < N_NODES ? gr : N_NODES - 1;
    const float* xrow = x + (size_t)grc * F_IN + lk;

    float acc[4][8];
#pragma unroll
    for (int i = 0; i < 4; ++i)
#pragma unroll
        for (int j = 0; j < 8; ++j) acc[i][j] = 0.f;

    for (int k0 = 0; k0 < F_IN; k0 += BK) {
        float4 v = *(const float4*)(xrow + k0);
        const float4* w4 = (const float4*)(W1 + (size_t)k0 * F_HID);
        float4 wv0 = w4[tid];
        float4 wv1 = w4[tid + 256];

        xT[lk + 0][lr] = v.x;
        xT[lk + 1][lr] = v.y;
        xT[lk + 2][lr] = v.z;
        xT[lk + 3][lr] = v.w;
        ((float4*)wt)[tid] = wv0;
        ((float4*)wt)[tid + 256] = wv1;
        __syncthreads();

#pragma unroll
        for (int k = 0; k < BK; ++k) {
            float a[4], b[8];
            *(float4*)a = *(const float4*)&xT[k][r0];
            *(float4*)(b + 0) = *(const float4*)&wt[k][c0];
            *(float4*)(b + 4) = *(const float4*)&wt[k][c0 + 4];
#pragma unroll
            for (int i = 0; i < 4; ++i)
#pragma unroll
                for (int j = 0; j < 8; ++j)
                    acc[i][j] = fmaf(a[i], b[j], acc[i][j]);
        }
        __syncthreads();
    }

#pragma unroll
    for (int i = 0; i < 4; ++i) {
        int n = m0 + r0 + i;
        if (n < N_NODES) {
            float s = dinv[n];
            uint4 o;
            o.x = pack_bf16(acc[i][0] * s, acc[i][1] * s);
            o.y = pack_bf16(acc[i][2] * s, acc[i][3] * s);
            o.z = pack_bf16(acc[i][4] * s, acc[i][5] * s);
            o.w = pack_bf16(acc[i][6] * s, acc[i][7] * s);
            *(uint4*)(g1u + (size_t)n * 64 + (c0 >> 1)) = o;
        }
    }
}

// ------- pull layer1 + relu/bias + GEMM2 fused, one wave per dst node -------
// 4-deep edge unroll: 16 cache lines in flight per wave (MLP)
__global__ __launch_bounds__(256) void k_pull1_gemm2(const int* __restrict__ csr,
                                                     const int* __restrict__ deg_i,
                                                     const unsigned* __restrict__ g1u,
                                                     const float* __restrict__ dinv,
                                                     const float* __restrict__ b1,
                                                     const float* __restrict__ W2,
                                                     unsigned* __restrict__ g2u) {
    __shared__ float w2l[F_HID * F_OUT];
    __shared__ float al[4][F_HID];
    {
        const float4* w4 = (const float4*)W2;
        float4* wl4 = (float4*)w2l;
#pragma unroll
        for (int i = 0; i < 4; ++i)
            wl4[threadIdx.x + i * 256] = w4[threadIdx.x + i * 256];
    }
    int lane = threadIdx.x & 63;
    int wv = threadIdx.x >> 6;
    int n = blockIdx.x * 4 + wv;

    unsigned u0 = g1u[(size_t)n * 64 + lane];  // self-loop
    float a0x = lo16(u0), a0y = hi16(u0);
    float a1x = 0.f, a1y = 0.f, a2x = 0.f, a2y = 0.f, a3x = 0.f, a3y = 0.f;
    int deg = deg_i[n];
    if (deg > CAP) deg = CAP;
    const int* crow = csr + (size_t)n * CAP;
    for (int e0 = 0; e0 < deg; e0 += 64) {
        int rem = deg - e0;
        int m = rem < 64 ? rem : 64;
        int sidx = (lane < m) ? __builtin_nontemporal_load(crow + e0 + lane) : 0;
        int j = 0;
        for (; j + 3 < m; j += 4) {
            int s0 = __shfl(sidx, j);
            int s1 = __shfl(sidx, j + 1);
            int s2 = __shfl(sidx, j + 2);
            int s3 = __shfl(sidx, j + 3);
            unsigned v0 = g1u[(size_t)s0 * 64 + lane];
            unsigned v1 = g1u[(size_t)s1 * 64 + lane];
            unsigned v2 = g1u[(size_t)s2 * 64 + lane];
            unsigned v3 = g1u[(size_t)s3 * 64 + lane];
            a0x += lo16(v0); a0y += hi16(v0);
            a1x += lo16(v1); a1y += hi16(v1);
            a2x += lo16(v2); a2y += hi16(v2);
            a3x += lo16(v3); a3y += hi16(v3);
        }
        for (; j < m; ++j) {
            int s0 = __shfl(sidx, j);
            unsigned v0 = g1u[(size_t)s0 * 64 + lane];
            a0x += lo16(v0); a0y += hi16(v0);
        }
    }
    float ax = (a0x + a1x) + (a2x + a3x);
    float ay = (a0y + a1y) + (a2y + a3y);

    float di = dinv[n];
    float2 bb = *(const float2*)(b1 + lane * 2);
    float a0 = fmaxf(fmaf(di, ax, bb.x), 0.f);
    float a1 = fmaxf(fmaf(di, ay, bb.y), 0.f);
    *(float2*)(&al[wv][lane * 2]) = make_float2(a0, a1);
    __syncthreads();

    int j = lane & 31, kh = lane >> 5;
    float sum = 0.f;
#pragma unroll
    for (int kk = 0; kk < 64; ++kk) {
        int k = kh * 64 + kk;
        sum = fmaf(al[wv][k], w2l[k * F_OUT + j], sum);
    }
    sum += __shfl_xor(sum, 32);
    float sv = sum * di;  // valid on lanes 0..31
    int fl16 = lane & 15;
    float sa = __shfl(sv, fl16 * 2);
    float sb = __shfl(sv, fl16 * 2 + 1);
    if (lane < 16) g2u[(size_t)n * 16 + fl16] = pack_bf16(sa, sb);
}

// ------- pull layer2 + bias, quarter-wave (16 lanes) per dst node -------
__global__ __launch_bounds__(256) void k_pull2(const int* __restrict__ csr,
                                               const int* __restrict__ deg_i,
                                               const unsigned* __restrict__ g2u,
                                               const float* __restrict__ dinv,
                                               const float* __restrict__ b2,
                                               float* __restrict__ out) {
    int lane = threadIdx.x & 63;
    int wv = threadIdx.x >> 6;
    int qw = lane >> 4, fl = lane & 15;
    int n = blockIdx.x * 16 + wv * 4 + qw;

    unsigned u0 = g2u[(size_t)n * 16 + fl];  // self-loop
    float a0x = lo16(u0), a0y = hi16(u0);
    float a1x = 0.f, a1y = 0.f, a2x = 0.f, a2y = 0.f, a3x = 0.f, a3y = 0.f;
    int deg = deg_i[n];
    if (deg > CAP) deg = CAP;
    const int* crow = csr + (size_t)n * CAP;
    for (int e0 = 0; e0 < deg; e0 += 16) {
        int rem = deg - e0;
        int m = rem < 16 ? rem : 16;
        int sidx = (fl < m) ? __builtin_nontemporal_load(crow + e0 + fl) : 0;
        int j = 0;
        for (; j + 3 < m; j += 4) {
            int s0 = __shfl(sidx, j, 16);
            int s1 = __shfl(sidx, j + 1, 16);
            int s2 = __shfl(sidx, j + 2, 16);
            int s3 = __shfl(sidx, j + 3, 16);
            unsigned v0 = g2u[(size_t)s0 * 16 + fl];
            unsigned v1 = g2u[(size_t)s1 * 16 + fl];
            unsigned v2 = g2u[(size_t)s2 * 16 + fl];
            unsigned v3 = g2u[(size_t)s3 * 16 + fl];
            a0x += lo16(v0); a0y += hi16(v0);
            a1x += lo16(v1); a1y += hi16(v1);
            a2x += lo16(v2); a2y += hi16(v2);
            a3x += lo16(v3); a3y += hi16(v3);
        }
        for (; j < m; ++j) {
            int s0 = __shfl(sidx, j, 16);
            unsigned v0 = g2u[(size_t)s0 * 16 + fl];
            a0x += lo16(v0); a0y += hi16(v0);
        }
    }
    float ax = (a0x + a1x) + (a2x + a3x);
    float ay = (a0y + a1y) + (a2y + a3y);

    float di = dinv[n];
    float2 bb = *(const float2*)(b2 + fl * 2);
    f32x2 o;
    o.x = fmaf(di, ax, bb.x);
    o.y = fmaf(di, ay, bb.y);
    __builtin_nontemporal_store(o, (f32x2*)(out + (size_t)n * F_OUT + fl * 2));
}

extern "C" void kernel_launch(void* const* d_in, const int* in_sizes, int n_in,
                              void* d_out, int out_size, void* d_ws, size_t ws_size,
                              hipStream_t stream) {
    const float* x  = (const float*)d_in[0];
    const int*   ei = (const int*)d_in[1];
    const float* W1 = (const float*)d_in[2];
    const float* b1 = (const float*)d_in[3];
    const float* W2 = (const float*)d_in[4];
    const float* b2 = (const float*)d_in[5];
    float* out = (float*)d_out;

    char* ws = (char*)d_ws;
    int*      deg   = (int*)(ws);                        // 400 KB (pad 512 KB)
    float*    dinv  = (float*)(ws + 524288);             // 400 KB (pad 512 KB)
    int*      gcur  = (int*)(ws + 1048576);              // 4 KB (pad 512 KB)
    int*      csr   = (int*)(ws + 1572864);              // 38.4 MB
    unsigned long long* stage = (unsigned long long*)(ws + 40000000);  // 28.0 MB
    unsigned* g1u   = (unsigned*)(ws + 68028416);        // 25.6 MB
    unsigned* g2u   = (unsigned*)(ws + 93628416);        // 6.4 MB (end ~100 MB)

    (void)hipMemsetAsync(gcur, 0, 4096, stream);
    k_part<<<(N_EDGES + 256 * EPT - 1) / (256 * EPT), 256, 0, stream>>>(ei, gcur, stage);
    k_csr<<<NBUCK, 256, 0, stream>>>(stage, gcur, csr, deg, dinv);

    k_gemm1<<<(N_NODES + BM - 1) / BM, 256, 0, stream>>>(x, W1, dinv, g1u);

    k_pull1_gemm2<<<N_NODES / 4, 256, 0, stream>>>(csr, deg, g1u, dinv, b1, W2, g2u);
    k_pull2<<<N_NODES / 16, 256, 0, stream>>>(csr, deg, g2u, dinv, b2, out);
}